// Round 8
// baseline (13434.956 us; speedup 1.0000x reference)
//
#include <hip/hip_runtime.h>

constexpr int kB = 64;
constexpr int kT = 1024;
constexpr int kC = 128;
constexpr int kH = 512;

constexpr int kWgPerGrp  = 32;   // wgs per group (16 cols each)
constexpr int kRows      = 4;    // batches per group
constexpr int kHStride   = 652;  // hbuf row: 512 h + 128 x + 12 pad floats
constexpr int kRingSlots = 8;    // h-exchange ring depth (2MB in d_ws)

#define SCOPE_AGENT __HIP_MEMORY_SCOPE_AGENT

__device__ __forceinline__ float sigmoidf_(float v) {
    return 1.0f / (1.0f + __expf(-v));
}

// Persistent GRU, DATAFLOW sync (no per-step barrier).
// 512 wgs x 256 threads, 2 wgs/CU. 16 groups x 32 wgs (R7 mapping: each XCD
// hosts 2 groups; each CU one wg of each -> anti-phased latency hiding).
// Group g owns batches [g*4, g*4+4); wg owns columns [jb*16, jb*16+16).
//
// h-exchange: 8-deep ring of atomic u64 = (epoch<<32)|float_bits in d_ws.
// Publisher: one relaxed agent-scope u64 store per output (value+epoch in ONE
// atom -> no fences, no flag, no publish-ack wait). Consumer: issue all 8
// staging loads up-front, overlap latency with x-part FMAs, retry only stale
// words (first try hits in steady state). Write-after-read protection: slot
// t&7 is re-written at t+8 and read at t+1, so publishers at step t check lazy
// progress flags (prog[wg] = last staged step + 1) against threshold t-6,
// prefetched at step start -> never blocks in steady state (lag ~1 << 7).
// No epoch aliasing across graph replays: ring memset to 0xFF each launch.
//
// Weights in registers (R7): whR[4][3][2] + wiR[3][2]. LDS = hbuf only.
// Thread map/tiling/reduce-scatter identical to R7 (verified).
__global__ __launch_bounds__(256, 2)
void gru_seq_kernel(const float* __restrict__ x,
                    const float* __restrict__ h0,
                    const float* __restrict__ w_ih,
                    const float* __restrict__ w_hh,
                    const float* __restrict__ b_ih,
                    const float* __restrict__ b_hh,
                    float* __restrict__ hs_out,    // d_out, [B,T,H]
                    float* __restrict__ h_final,   // d_out + B*T*H
                    unsigned* __restrict__ prog,   // d_ws: 16x32 u32, init 0
                    unsigned long long* __restrict__ ring) // d_ws+4KB, init FF
{
    const int wg  = blockIdx.x;
    const int q   = wg >> 3;
    const int grp = ((wg & 7) << 1) | (q & 1);   // 0..15
    const int jb  = q >> 1;                      // 0..31
    const int tid = threadIdx.x;
    const int jp  = tid >> 5;                    // 0..7 (j-pair)
    const int s   = tid & 31;                    // K-slice
    const int b0  = grp * kRows;

    __shared__ float hbuf[kRows][kHStride];      // 10,432 B

    // ---- one-time weight loads into REGISTERS (R7-verbatim) ----
    const float4* w_hh4 = (const float4*)w_hh;
    const float4* w_ih4 = (const float4*)w_ih;
    float4 whR[4][3][2];
    #pragma unroll
    for (int m = 0; m < 4; ++m)
        #pragma unroll
        for (int g = 0; g < 3; ++g)
            #pragma unroll
            for (int jj = 0; jj < 2; ++jj)
                whR[m][g][jj] =
                    w_hh4[((size_t)(g * kH + jb * 16 + jp * 2 + jj)) * (kH / 4)
                          + s + 32 * m];
    float4 wiR[3][2];
    #pragma unroll
    for (int g = 0; g < 3; ++g)
        #pragma unroll
        for (int jj = 0; jj < 2; ++jj)
            wiR[g][jj] =
                w_ih4[((size_t)(g * kH + jb * 16 + jp * 2 + jj)) * (kC / 4) + s];

    const int jg_f = jb * 16 + jp * 2 + ((s >> 1) & 1);
    const float brz = b_ih[jg_f]          + b_hh[jg_f];
    const float bzz = b_ih[kH + jg_f]     + b_hh[kH + jg_f];
    const float bxn = b_ih[2 * kH + jg_f];
    const float bhn = b_hh[2 * kH + jg_f];

    unsigned* myprog = prog + grp * kWgPerGrp + jb;
    const unsigned* pollprog = prog + grp * kWgPerGrp + (tid & 31);

    // staging geometry: wg covers 4 rows x 512 cols = 2048 u64; thread owns 8
    // consecutive u64 (one row, cols [tid*8 & 511, +8))
    const int st_flat = tid * 8;
    const int st_row  = st_flat >> 9;          // 0..3
    const int st_col  = st_flat & 511;

    // ---- prologue: stage h0 and x(0) into LDS ----
    #pragma unroll
    for (int qq = 0; qq < 2; ++qq) {
        const int idx = tid + qq * 256;
        const int row = idx >> 7;
        const int f4  = idx & 127;
        *(float4*)&hbuf[row][f4 * 4] =
            *(const float4*)&h0[(size_t)(b0 + row) * kH + f4 * 4];
    }
    if (tid < 128) {
        const int row = tid >> 5;
        const int f4i = tid & 31;
        *(float4*)&hbuf[row][512 + f4i * 4] =
            *(const float4*)&x[((size_t)(b0 + row) * kT + 0) * kC + f4i * 4];
    }
    __syncthreads();

    for (int t = 0; t < kT; ++t) {
        // ---- issue staging loads (slot t-1) and prog prefetch, no waits ----
        unsigned long long* rp =
            ring + ((size_t)((t - 1) & 7) * kB + (b0 + st_row)) * kH + st_col;
        unsigned long long v[8];
        if (t > 0) {
            #pragma unroll
            for (int qq = 0; qq < 8; ++qq)
                v[qq] = __hip_atomic_load(rp + qq, __ATOMIC_RELAXED, SCOPE_AGENT);
        }
        unsigned pv = 0xFFFFFFFFu;
        const bool need_gate = (t >= kRingSlots - 1);
        if (need_gate)
            pv = __hip_atomic_load(pollprog, __ATOMIC_RELAXED, SCOPE_AGENT);

        // ---- x-part FMAs first (overlaps staging-load latency) ----
        float acc[4][4][2];
        #pragma unroll
        for (int g = 0; g < 4; ++g)
            #pragma unroll
            for (int i = 0; i < 4; ++i) {
                acc[g][i][0] = 0.f; acc[g][i][1] = 0.f;
            }
        {
            float4 x4v[4];
            #pragma unroll
            for (int i = 0; i < 4; ++i)
                x4v[i] = *(const float4*)(&hbuf[i][512 + s * 4]);
            #pragma unroll
            for (int g = 0; g < 3; ++g) {
                const int ga = (g == 2) ? 3 : g;
                #pragma unroll
                for (int jj = 0; jj < 2; ++jj) {
                    const float4 w4 = wiR[g][jj];
                    #pragma unroll
                    for (int i = 0; i < 4; ++i)
                        acc[ga][i][jj] += x4v[i].x * w4.x + x4v[i].y * w4.y
                                        + x4v[i].z * w4.z + x4v[i].w * w4.w;
                }
            }
        }

        // ---- consume staging: retry stale words, unpack, write LDS ----
        if (t > 0) {
            const unsigned et = (unsigned)(t - 1);
            #pragma unroll
            for (int qq = 0; qq < 8; ++qq)
                while ((unsigned)(v[qq] >> 32) != et)
                    v[qq] = __hip_atomic_load(rp + qq, __ATOMIC_RELAXED, SCOPE_AGENT);
            float4 f0, f1;
            f0.x = __uint_as_float((unsigned)v[0]);
            f0.y = __uint_as_float((unsigned)v[1]);
            f0.z = __uint_as_float((unsigned)v[2]);
            f0.w = __uint_as_float((unsigned)v[3]);
            f1.x = __uint_as_float((unsigned)v[4]);
            f1.y = __uint_as_float((unsigned)v[5]);
            f1.z = __uint_as_float((unsigned)v[6]);
            f1.w = __uint_as_float((unsigned)v[7]);
            *(float4*)&hbuf[st_row][st_col]     = f0;
            *(float4*)&hbuf[st_row][st_col + 4] = f1;
        }
        __syncthreads();   // staging visible; x(t) reads done before x(t+1) writes

        // staging of step t consumed -> publish progress (lazy, one lane)
        if (tid == 0)
            __hip_atomic_store(myprog, (unsigned)(t + 1), __ATOMIC_RELAXED, SCOPE_AGENT);

        // ---- prefetch x for step t+1 ----
        if (t + 1 < kT && tid < 128) {
            const int row = tid >> 5;
            const int f4i = tid & 31;
            *(float4*)&hbuf[row][512 + f4i * 4] =
                *(const float4*)&x[((size_t)(b0 + row) * kT + (t + 1)) * kC + f4i * 4];
        }

        // ---- h-part FMAs (R7-verbatim) ----
        const float* hbase = &hbuf[0][s * 4];
        #pragma unroll
        for (int m = 0; m < 4; ++m) {
            const int off = m * 128;
            float4 h4[4];
            #pragma unroll
            for (int i = 0; i < 4; ++i)
                h4[i] = *(const float4*)(hbase + i * kHStride + off);
            #pragma unroll
            for (int g = 0; g < 3; ++g)
                #pragma unroll
                for (int jj = 0; jj < 2; ++jj) {
                    const float4 w4 = whR[m][g][jj];
                    #pragma unroll
                    for (int i = 0; i < 4; ++i)
                        acc[g][i][jj] += h4[i].x * w4.x + h4[i].y * w4.y
                                       + h4[i].z * w4.z + h4[i].w * w4.w;
                }
        }

        // ---- reduce-scatter xor{8,4,2} + butterflies xor{16,1} (R7) ----
        const bool b3 = (s >> 3) & 1;
        const bool b2 = (s >> 2) & 1;
        const bool b1 = (s >> 1) & 1;

        float A[4][2][2];
        #pragma unroll
        for (int g = 0; g < 4; ++g)
            #pragma unroll
            for (int ii = 0; ii < 2; ++ii)
                #pragma unroll
                for (int jj = 0; jj < 2; ++jj) {
                    const float keep = b3 ? acc[g][2 + ii][jj] : acc[g][ii][jj];
                    const float send = b3 ? acc[g][ii][jj] : acc[g][2 + ii][jj];
                    A[g][ii][jj] = keep + __shfl_xor(send, 8);
                }
        float Bv[4][2];
        #pragma unroll
        for (int g = 0; g < 4; ++g)
            #pragma unroll
            for (int jj = 0; jj < 2; ++jj) {
                const float keep = b2 ? A[g][1][jj] : A[g][0][jj];
                const float send = b2 ? A[g][0][jj] : A[g][1][jj];
                Bv[g][jj] = keep + __shfl_xor(send, 4);
            }
        float Dv[4];
        #pragma unroll
        for (int g = 0; g < 4; ++g) {
            const float keep = b1 ? Bv[g][1] : Bv[g][0];
            const float send = b1 ? Bv[g][0] : Bv[g][1];
            float c = keep + __shfl_xor(send, 2);
            c += __shfl_xor(c, 16);
            c += __shfl_xor(c, 1);
            Dv[g] = c;
        }

        // ---- ring-reuse gate (prefetched; steady state: no retry) ----
        if (need_gate) {
            const unsigned need = (unsigned)(t - (kRingSlots - 2));   // t-6
            while (__any((int)(pv < need)))
                pv = __hip_atomic_load(pollprog, __ATOMIC_RELAXED, SCOPE_AGENT);
        }

        // ---- finish + publish (even lanes s<16; row = b3*2+b2, jj = b1) ----
        if (s < 16 && (s & 1) == 0) {
            const int   row  = ((s >> 3) & 1) * 2 + ((s >> 2) & 1);
            const int   bg   = b0 + row;
            const float rg   = sigmoidf_(Dv[0] + brz);
            const float zg   = sigmoidf_(Dv[1] + bzz);
            const float ng   = tanhf(Dv[3] + bxn + rg * (Dv[2] + bhn));
            const float hold = hbuf[row][jg_f];
            const float hnew = (1.f - zg) * ng + zg * hold;

            const unsigned long long pk =
                ((unsigned long long)(unsigned)t << 32) | (unsigned long long)__float_as_uint(hnew);
            __hip_atomic_store(ring + ((size_t)(t & 7) * kB + bg) * kH + jg_f,
                               pk, __ATOMIC_RELAXED, SCOPE_AGENT);
            hs_out[((size_t)bg * kT + t) * kH + jg_f] = hnew;   // plain store
            if (t == kT - 1) h_final[(size_t)bg * kH + jg_f] = hnew;
        }

        __syncthreads();   // hbuf reads of step t done before t+1 overwrites
    }
}

// In-place post projection: out[b,t,:] = relu(hs[b,t,:] @ w_post^T + b_post).
__global__ __launch_bounds__(256, 1)
void post_kernel(const float* __restrict__ w_post,
                 const float* __restrict__ b_post,
                 float* __restrict__ out)
{
    __shared__ float hbuf[16][kH];
    const int tid = threadIdx.x;
    const size_t row0 = (size_t)blockIdx.x * 16;

    const float4* src = (const float4*)(out + row0 * kH);
    float4* hb4 = (float4*)hbuf;
    for (int i = tid; i < 16 * kH / 4; i += 256) hb4[i] = src[i];
    __syncthreads();

    for (int pass = 0; pass < 2; ++pass) {
        const int d = tid + pass * 256;
        const float4* wrow = (const float4*)(w_post + (size_t)d * kH);
        float acc[16];
        #pragma unroll
        for (int m = 0; m < 16; ++m) acc[m] = 0.f;
        for (int k4 = 0; k4 < kH / 4; ++k4) {
            const float4 w4 = wrow[k4];
            #pragma unroll
            for (int m = 0; m < 16; ++m) {
                const float4 h4 = *(const float4*)&hbuf[m][k4 * 4];
                acc[m] += h4.x * w4.x + h4.y * w4.y + h4.z * w4.z + h4.w * w4.w;
            }
        }
        const float bp = b_post[d];
        #pragma unroll
        for (int m = 0; m < 16; ++m) {
            out[(row0 + m) * kH + d] = fmaxf(acc[m] + bp, 0.f);
        }
    }
}

extern "C" void kernel_launch(void* const* d_in, const int* in_sizes, int n_in,
                              void* d_out, int out_size, void* d_ws, size_t ws_size,
                              hipStream_t stream) {
    const float* x      = (const float*)d_in[0];
    const float* h0     = (const float*)d_in[1];
    const float* w_ih   = (const float*)d_in[2];
    const float* w_hh   = (const float*)d_in[3];
    const float* b_ih   = (const float*)d_in[4];
    const float* b_hh   = (const float*)d_in[5];
    const float* w_post = (const float*)d_in[6];
    const float* b_post = (const float*)d_in[7];

    float* out     = (float*)d_out;
    float* h_final = out + (size_t)kB * kT * kH;

    unsigned* progf = (unsigned*)d_ws;                               // 2 KB used
    unsigned long long* ring = (unsigned long long*)((char*)d_ws + 4096);
    const size_t ring_bytes = (size_t)kRingSlots * kB * kH * 8;      // 2 MB

    // Per-launch init (graph-replay safe): prog = 0, ring epochs = 0xFF
    // (real epochs are 0..1023, so no aliasing across replays).
    hipMemsetAsync(d_ws, 0, 4096, stream);
    hipMemsetAsync((char*)d_ws + 4096, 0xFF, ring_bytes, stream);

    void* args[] = { (void*)&x, (void*)&h0, (void*)&w_ih, (void*)&w_hh,
                     (void*)&b_ih, (void*)&b_hh, (void*)&out, (void*)&h_final,
                     (void*)&progf, (void*)&ring };
    // Cooperative launch for guaranteed co-residency (dataflow requires it);
    // fall back to plain launch (2 wg/CU co-resident in practice).
    hipError_t err = hipLaunchCooperativeKernel((void*)gru_seq_kernel,
                                                dim3(512), dim3(256),
                                                args, 0, stream);
    if (err != hipSuccess) {
        gru_seq_kernel<<<dim3(512), dim3(256), 0, stream>>>(
            x, h0, w_ih, w_hh, b_ih, b_hh, out, h_final, progf, ring);
    }

    post_kernel<<<dim3(kB * kT / 16), dim3(256), 0, stream>>>(w_post, b_post, out);
}

// Round 9
// 8841.540 us; speedup vs baseline: 1.5195x; 1.5195x over previous
//
#include <hip/hip_runtime.h>

constexpr int kB = 64;
constexpr int kT = 1024;
constexpr int kC = 128;
constexpr int kH = 512;

constexpr int kWgPerGrp  = 32;   // wgs per group (16 cols each)
constexpr int kRows      = 4;    // batches per group
constexpr int kHStride   = 652;  // hbuf row: 512 h + 128 x + 12 pad floats
constexpr int kRingSlots = 8;    // h-exchange ring depth (2MB in d_ws)

#define SCOPE_AGENT __HIP_MEMORY_SCOPE_AGENT

__device__ __forceinline__ float sigmoidf_(float v) {
    return 1.0f / (1.0f + __expf(-v));
}

// Persistent GRU, DATAFLOW sync (no flags in the per-step critical path).
// 512 wgs x 256 threads, 2 wgs/CU. 16 groups x 32 wgs (R7 mapping: each XCD
// hosts 2 groups; each CU one wg of each -> anti-phased latency hiding).
// Group g owns batches [g*4, g*4+4); wg owns columns [jb*16, jb*16+16).
//
// h-exchange: 8-deep ring of u64 = (epoch<<32)|float_bits in d_ws (2MB,
// L3-resident). Publisher: one relaxed agent-scope u64 store per output
// (value+epoch in ONE atom -> no fence, no flag, no publish-ack wait).
// Consumer: COALESCED speculative loads (thread reads flat idx tid + qq*256;
// each instruction = 64 lanes x 8B contiguous = 512B MALL burst), overlapped
// with x-part FMAs; wave-collective retry on stale epochs (rare, coalesced).
// [R8 failed here: per-thread-consecutive layout made every load instruction
//  64 scattered 8B MALL transactions (8x over-fetch) + 8-way LDS conflicts.]
// Write-after-read over the 8-slot ring: publisher at step t overwrites epoch
// t-8 (consumed at partners' step t-7), gated by lazy progress flags
// (prog[wg] = steps staged) vs threshold t-6, prefetched at step start ->
// never blocks in steady state (skew ~1 step << 7).
// Ring memset 0xFF per launch: epochs 0..1023 never alias across replays.
//
// Weights in registers (R7): whR[4][3][2] + wiR[3][2]. LDS = hbuf only.
// Thread map/tiling/reduce-scatter identical to R7 (verified twice).
__global__ __launch_bounds__(256, 2)
void gru_seq_kernel(const float* __restrict__ x,
                    const float* __restrict__ h0,
                    const float* __restrict__ w_ih,
                    const float* __restrict__ w_hh,
                    const float* __restrict__ b_ih,
                    const float* __restrict__ b_hh,
                    float* __restrict__ hs_out,    // d_out, [B,T,H]
                    float* __restrict__ h_final,   // d_out + B*T*H
                    unsigned* __restrict__ prog,   // d_ws: 16x32 u32, init 0
                    unsigned long long* __restrict__ ring) // d_ws+4KB, init FF
{
    const int wg  = blockIdx.x;
    const int q   = wg >> 3;
    const int grp = ((wg & 7) << 1) | (q & 1);   // 0..15
    const int jb  = q >> 1;                      // 0..31
    const int tid = threadIdx.x;
    const int jp  = tid >> 5;                    // 0..7 (j-pair)
    const int s   = tid & 31;                    // K-slice
    const int b0  = grp * kRows;

    __shared__ float hbuf[kRows][kHStride];      // 10,432 B

    // ---- one-time weight loads into REGISTERS (R7-verbatim) ----
    const float4* w_hh4 = (const float4*)w_hh;
    const float4* w_ih4 = (const float4*)w_ih;
    float4 whR[4][3][2];
    #pragma unroll
    for (int m = 0; m < 4; ++m)
        #pragma unroll
        for (int g = 0; g < 3; ++g)
            #pragma unroll
            for (int jj = 0; jj < 2; ++jj)
                whR[m][g][jj] =
                    w_hh4[((size_t)(g * kH + jb * 16 + jp * 2 + jj)) * (kH / 4)
                          + s + 32 * m];
    float4 wiR[3][2];
    #pragma unroll
    for (int g = 0; g < 3; ++g)
        #pragma unroll
        for (int jj = 0; jj < 2; ++jj)
            wiR[g][jj] =
                w_ih4[((size_t)(g * kH + jb * 16 + jp * 2 + jj)) * (kC / 4) + s];

    const int jg_f = jb * 16 + jp * 2 + ((s >> 1) & 1);
    const float brz = b_ih[jg_f]          + b_hh[jg_f];
    const float bzz = b_ih[kH + jg_f]     + b_hh[kH + jg_f];
    const float bxn = b_ih[2 * kH + jg_f];
    const float bhn = b_hh[2 * kH + jg_f];

    unsigned* myprog = prog + grp * kWgPerGrp + jb;
    const unsigned* pollprog = prog + grp * kWgPerGrp + (tid & 31);

    // ---- prologue: stage h0 and x(0) into LDS ----
    #pragma unroll
    for (int qq = 0; qq < 2; ++qq) {
        const int idx = tid + qq * 256;
        const int row = idx >> 7;
        const int f4  = idx & 127;
        *(float4*)&hbuf[row][f4 * 4] =
            *(const float4*)&h0[(size_t)(b0 + row) * kH + f4 * 4];
    }
    if (tid < 128) {
        const int row = tid >> 5;
        const int f4i = tid & 31;
        *(float4*)&hbuf[row][512 + f4i * 4] =
            *(const float4*)&x[((size_t)(b0 + row) * kT + 0) * kC + f4i * 4];
    }
    __syncthreads();

    for (int t = 0; t < kT; ++t) {
        // ---- speculative COALESCED ring loads (slot t-1), no waits ----
        // flat index f = tid + qq*256 in [0,2048): row = f>>9, col = f&511.
        const unsigned long long* rp =
            ring + (size_t)((t - 1) & 7) * (kB * kH) + (size_t)b0 * kH;
        unsigned long long v[8];
        if (t > 0) {
            #pragma unroll
            for (int qq = 0; qq < 8; ++qq)
                v[qq] = __hip_atomic_load(rp + tid + qq * 256,
                                          __ATOMIC_RELAXED, SCOPE_AGENT);
        }
        unsigned pv = 0xFFFFFFFFu;
        const bool need_gate = (t >= kRingSlots - 1);
        if (need_gate)
            pv = __hip_atomic_load(pollprog, __ATOMIC_RELAXED, SCOPE_AGENT);

        // ---- x-part FMAs first (overlaps staging-load latency) ----
        float acc[4][4][2];
        #pragma unroll
        for (int g = 0; g < 4; ++g)
            #pragma unroll
            for (int i = 0; i < 4; ++i) {
                acc[g][i][0] = 0.f; acc[g][i][1] = 0.f;
            }
        {
            float4 x4v[4];
            #pragma unroll
            for (int i = 0; i < 4; ++i)
                x4v[i] = *(const float4*)(&hbuf[i][512 + s * 4]);
            #pragma unroll
            for (int g = 0; g < 3; ++g) {
                const int ga = (g == 2) ? 3 : g;
                #pragma unroll
                for (int jj = 0; jj < 2; ++jj) {
                    const float4 w4 = wiR[g][jj];
                    #pragma unroll
                    for (int i = 0; i < 4; ++i)
                        acc[ga][i][jj] += x4v[i].x * w4.x + x4v[i].y * w4.y
                                        + x4v[i].z * w4.z + x4v[i].w * w4.w;
                }
            }
        }

        // ---- consume staging: wave-collective retry, conflict-free LDS ----
        if (t > 0) {
            const unsigned et = (unsigned)(t - 1);
            while (true) {
                bool stale = false;
                #pragma unroll
                for (int qq = 0; qq < 8; ++qq)
                    stale |= ((unsigned)(v[qq] >> 32) != et);
                if (!__any((int)stale)) break;
                #pragma unroll
                for (int qq = 0; qq < 8; ++qq)
                    v[qq] = __hip_atomic_load(rp + tid + qq * 256,
                                              __ATOMIC_RELAXED, SCOPE_AGENT);
            }
            #pragma unroll
            for (int qq = 0; qq < 8; ++qq) {
                const int f = tid + qq * 256;
                hbuf[f >> 9][f & 511] = __uint_as_float((unsigned)v[qq]);
            }
        }
        __syncthreads();   // staging visible; x(t) reads done before x(t+1) writes

        // staging of slot t-1 consumed -> publish progress (lazy, one lane)
        if (tid == 0)
            __hip_atomic_store(myprog, (unsigned)(t + 1), __ATOMIC_RELAXED, SCOPE_AGENT);

        // ---- prefetch x for step t+1 ----
        if (t + 1 < kT && tid < 128) {
            const int row = tid >> 5;
            const int f4i = tid & 31;
            *(float4*)&hbuf[row][512 + f4i * 4] =
                *(const float4*)&x[((size_t)(b0 + row) * kT + (t + 1)) * kC + f4i * 4];
        }

        // ---- h-part FMAs (R7-verbatim) ----
        const float* hbase = &hbuf[0][s * 4];
        #pragma unroll
        for (int m = 0; m < 4; ++m) {
            const int off = m * 128;
            float4 h4[4];
            #pragma unroll
            for (int i = 0; i < 4; ++i)
                h4[i] = *(const float4*)(hbase + i * kHStride + off);
            #pragma unroll
            for (int g = 0; g < 3; ++g)
                #pragma unroll
                for (int jj = 0; jj < 2; ++jj) {
                    const float4 w4 = whR[m][g][jj];
                    #pragma unroll
                    for (int i = 0; i < 4; ++i)
                        acc[g][i][jj] += h4[i].x * w4.x + h4[i].y * w4.y
                                       + h4[i].z * w4.z + h4[i].w * w4.w;
                }
        }

        // ---- reduce-scatter xor{8,4,2} + butterflies xor{16,1} (R7) ----
        const bool b3 = (s >> 3) & 1;
        const bool b2 = (s >> 2) & 1;
        const bool b1 = (s >> 1) & 1;

        float A[4][2][2];
        #pragma unroll
        for (int g = 0; g < 4; ++g)
            #pragma unroll
            for (int ii = 0; ii < 2; ++ii)
                #pragma unroll
                for (int jj = 0; jj < 2; ++jj) {
                    const float keep = b3 ? acc[g][2 + ii][jj] : acc[g][ii][jj];
                    const float send = b3 ? acc[g][ii][jj] : acc[g][2 + ii][jj];
                    A[g][ii][jj] = keep + __shfl_xor(send, 8);
                }
        float Bv[4][2];
        #pragma unroll
        for (int g = 0; g < 4; ++g)
            #pragma unroll
            for (int jj = 0; jj < 2; ++jj) {
                const float keep = b2 ? A[g][1][jj] : A[g][0][jj];
                const float send = b2 ? A[g][0][jj] : A[g][1][jj];
                Bv[g][jj] = keep + __shfl_xor(send, 4);
            }
        float Dv[4];
        #pragma unroll
        for (int g = 0; g < 4; ++g) {
            const float keep = b1 ? Bv[g][1] : Bv[g][0];
            const float send = b1 ? Bv[g][0] : Bv[g][1];
            float c = keep + __shfl_xor(send, 2);
            c += __shfl_xor(c, 16);
            c += __shfl_xor(c, 1);
            Dv[g] = c;
        }

        // ---- ring-reuse gate (prefetched; steady state: no retry) ----
        if (need_gate) {
            const unsigned need = (unsigned)(t - (kRingSlots - 2));   // t-6
            while (__any((int)(pv < need)))
                pv = __hip_atomic_load(pollprog, __ATOMIC_RELAXED, SCOPE_AGENT);
        }

        // ---- finish + publish (even lanes s<16; row = b3*2+b2, jj = b1) ----
        if (s < 16 && (s & 1) == 0) {
            const int   row  = ((s >> 3) & 1) * 2 + ((s >> 2) & 1);
            const int   bg   = b0 + row;
            const float rg   = sigmoidf_(Dv[0] + brz);
            const float zg   = sigmoidf_(Dv[1] + bzz);
            const float ng   = tanhf(Dv[3] + bxn + rg * (Dv[2] + bhn));
            const float hold = hbuf[row][jg_f];
            const float hnew = (1.f - zg) * ng + zg * hold;

            const unsigned long long pk =
                ((unsigned long long)(unsigned)t << 32)
                | (unsigned long long)__float_as_uint(hnew);
            __hip_atomic_store(ring + (size_t)(t & 7) * (kB * kH)
                                   + (size_t)bg * kH + jg_f,
                               pk, __ATOMIC_RELAXED, SCOPE_AGENT);
            hs_out[((size_t)bg * kT + t) * kH + jg_f] = hnew;   // plain store
            if (t == kT - 1) h_final[(size_t)bg * kH + jg_f] = hnew;
        }

        __syncthreads();   // hbuf reads of step t done before t+1 overwrites
    }
}

// In-place post projection: out[b,t,:] = relu(hs[b,t,:] @ w_post^T + b_post).
__global__ __launch_bounds__(256, 1)
void post_kernel(const float* __restrict__ w_post,
                 const float* __restrict__ b_post,
                 float* __restrict__ out)
{
    __shared__ float hbuf[16][kH];
    const int tid = threadIdx.x;
    const size_t row0 = (size_t)blockIdx.x * 16;

    const float4* src = (const float4*)(out + row0 * kH);
    float4* hb4 = (float4*)hbuf;
    for (int i = tid; i < 16 * kH / 4; i += 256) hb4[i] = src[i];
    __syncthreads();

    for (int pass = 0; pass < 2; ++pass) {
        const int d = tid + pass * 256;
        const float4* wrow = (const float4*)(w_post + (size_t)d * kH);
        float acc[16];
        #pragma unroll
        for (int m = 0; m < 16; ++m) acc[m] = 0.f;
        for (int k4 = 0; k4 < kH / 4; ++k4) {
            const float4 w4 = wrow[k4];
            #pragma unroll
            for (int m = 0; m < 16; ++m) {
                const float4 h4 = *(const float4*)&hbuf[m][k4 * 4];
                acc[m] += h4.x * w4.x + h4.y * w4.y + h4.z * w4.z + h4.w * w4.w;
            }
        }
        const float bp = b_post[d];
        #pragma unroll
        for (int m = 0; m < 16; ++m) {
            out[(row0 + m) * kH + d] = fmaxf(acc[m] + bp, 0.f);
        }
    }
}

extern "C" void kernel_launch(void* const* d_in, const int* in_sizes, int n_in,
                              void* d_out, int out_size, void* d_ws, size_t ws_size,
                              hipStream_t stream) {
    const float* x      = (const float*)d_in[0];
    const float* h0     = (const float*)d_in[1];
    const float* w_ih   = (const float*)d_in[2];
    const float* w_hh   = (const float*)d_in[3];
    const float* b_ih   = (const float*)d_in[4];
    const float* b_hh   = (const float*)d_in[5];
    const float* w_post = (const float*)d_in[6];
    const float* b_post = (const float*)d_in[7];

    float* out     = (float*)d_out;
    float* h_final = out + (size_t)kB * kT * kH;

    unsigned* progf = (unsigned*)d_ws;                               // 2 KB used
    unsigned long long* ring = (unsigned long long*)((char*)d_ws + 4096);
    const size_t ring_bytes = (size_t)kRingSlots * kB * kH * 8;      // 2 MB

    // Per-launch init (graph-replay safe): prog = 0, ring epochs = 0xFF
    // (real epochs are 0..1023, so no aliasing across replays).
    hipMemsetAsync(d_ws, 0, 4096, stream);
    hipMemsetAsync((char*)d_ws + 4096, 0xFF, ring_bytes, stream);

    void* args[] = { (void*)&x, (void*)&h0, (void*)&w_ih, (void*)&w_hh,
                     (void*)&b_ih, (void*)&b_hh, (void*)&out, (void*)&h_final,
                     (void*)&progf, (void*)&ring };
    // Cooperative launch for guaranteed co-residency (dataflow requires it);
    // fall back to plain launch (2 wg/CU co-resident in practice).
    hipError_t err = hipLaunchCooperativeKernel((void*)gru_seq_kernel,
                                                dim3(512), dim3(256),
                                                args, 0, stream);
    if (err != hipSuccess) {
        gru_seq_kernel<<<dim3(512), dim3(256), 0, stream>>>(
            x, h0, w_ih, w_hh, b_ih, b_hh, out, h_final, progf, ring);
    }

    post_kernel<<<dim3(kB * kT / 16), dim3(256), 0, stream>>>(w_post, b_post, out);
}